// Round 5
// baseline (159.730 us; speedup 1.0000x reference)
//
#include <hip/hip_runtime.h>

// SlotElmanCell: T=1024, Bb=2, D=1024, S=64
//   decay = sigmoid(decay_logits)            [D,S]
//   h[t+1] = decay*h[t] + B*x[t]             [Bb,D,S]
//   out[t] = (h[t+1] . C) * silu(z[t])       [Bb,D]
// Outputs (concat flat): out [T,Bb,D] then h [T+1,Bb,D,S]  (f32)
//
// R5: temporal decomposition. R4 was 2 waves/SIMD (23% occupancy) and sat
// at 147us vs the 87us write floor. The recurrence is linear+diagonal:
// over a 64-step segment, h_end = decay^64 * h_start + local_scan(x).
//  Pass1: 32768 waves (chain,seg) compute local_scan from zero state -> ws.
//  Pass2: 32768 waves fold h0 + previous segments' local sums (weights
//         decay^64) to get the exact segment start state, then re-scan the
//         segment (R4 inner loop) writing h and out. 16x the TLP.

#define T_    1024
#define BB_   2
#define D_    1024
#define S_    64
#define SEG_  64              // steps per segment == wavefront size
#define NSEG_ (T_ / SEG_)     // 16
#define NCH_  (BB_ * D_)      // 2048 chains
#define STRD_ (BB_ * D_)      // x/z stride between timesteps
#define WS_NEED_ ((size_t)NCH_ * NSEG_ * S_ * 4)   // 8 MB

// x + dpp_shifted(x); bound_ctrl=1 -> out-of-range sources read 0.
#define DPP_ADD(x, ctrl, rm) \
  ((x) + __int_as_float(__builtin_amdgcn_update_dpp( \
        0, __float_as_int(x), (ctrl), (rm), 0xf, true)))

__device__ __forceinline__ float readlane_f(float v, int lane) {
    return __int_as_float(__builtin_amdgcn_readlane(__float_as_int(v), lane));
}

__device__ __forceinline__ float sigmoidf_(float v) {
    return 1.0f / (1.0f + __expf(-v));
}

// ---------------- Pass 1: per-segment local scans (zero init) -------------
__global__ __launch_bounds__(256, 8) void slot_elman_pass1(
    const float* __restrict__ x, const float* __restrict__ dl,
    const float* __restrict__ Bm, float* __restrict__ ws)
{
    const int wave = blockIdx.x * (blockDim.x >> 6) + (threadIdx.x >> 6);
    const int lane = threadIdx.x & 63;
    const int bd   = wave & (NCH_ - 1);     // chain
    const int seg  = wave >> 11;            // segment
    const int d    = bd & (D_ - 1);
    const int ds   = d * S_ + lane;

    const float decay = sigmoidf_(dl[ds]);
    const float Bv    = Bm[ds];

    // One gather: lane l holds x[seg*64 + l] for this chain
    const float xg = x[(size_t)(seg * SEG_ + lane) * STRD_ + bd];

    float hl = 0.0f;
    #pragma unroll
    for (int i = 0; i < SEG_; ++i)
        hl = fmaf(decay, hl, Bv * readlane_f(xg, i));

    ws[(size_t)(bd * NSEG_ + seg) * S_ + lane] = hl;
}

// ---------------- Pass 2: fold start state, re-scan, write h/out ----------
__global__ __launch_bounds__(256, 4) void slot_elman_pass2(
    const float* __restrict__ x, const float* __restrict__ z,
    const float* __restrict__ h0, const float* __restrict__ dl,
    const float* __restrict__ Bm, const float* __restrict__ C,
    const float* __restrict__ ws,
    float* __restrict__ out, float* __restrict__ h)
{
    // Chunked bijective XCD swizzle (8192 blocks, 1024/XCD)
    const int bid = blockIdx.x;
    const int cpx = gridDim.x >> 3;
    const int swz = (bid & 7) * cpx + (bid >> 3);

    const int wave = swz * (blockDim.x >> 6) + (threadIdx.x >> 6);
    const int lane = threadIdx.x & 63;
    const int bd   = wave & (NCH_ - 1);
    const int seg  = wave >> 11;
    const int d    = bd & (D_ - 1);
    const int ds   = d * S_ + lane;

    const float decay = sigmoidf_(dl[ds]);
    const float Bv    = Bm[ds];
    const float Cv    = C[lane];

    // decay^64 by repeated squaring
    float dk = decay * decay;   // ^2
    dk = dk * dk;               // ^4
    dk = dk * dk;               // ^8
    dk = dk * dk;               // ^16
    dk = dk * dk;               // ^32
    const float d64 = dk * dk;  // ^64

    // Segment start state: h0 folded with previous segments' local sums.
    float hv = h0[(size_t)bd * S_ + lane];
    if (seg == 0)
        h[(size_t)bd * S_ + lane] = hv;     // h[0] slice

    const float* wp = ws + (size_t)bd * NSEG_ * S_ + lane;
    #pragma unroll
    for (int j = 0; j < NSEG_ - 1; ++j) {   // 15 unconditional parallel loads
        const float lj = wp[(size_t)j * S_];
        const float w  = (j < seg) ? d64 : 1.0f;
        const float a  = (j < seg) ? lj  : 0.0f;
        hv = fmaf(w, hv, a);
    }

    // Gathers for this segment: lane l holds t = seg*64 + l
    const float xgA = x[(size_t)(seg * SEG_ + lane) * STRD_ + bd];
    const float zgA = z[(size_t)(seg * SEG_ + lane) * STRD_ + bd];

    // silu(z) for all 64 steps, vectorized (lane = t)
    const float sgv = zgA * sigmoidf_(zgA);

    // h[t+1] pointer for t = seg*64 (+1 slice for h0)
    float* hp = h + ((size_t)(seg * SEG_ + 1) * NCH_ + bd) * S_ + lane;
    float outacc = 0.0f;

    #pragma unroll 8
    for (int i = 0; i < SEG_; ++i) {
        const float xs = readlane_f(xgA, i);

        // Recurrence (only loop-carried dep)
        hv = fmaf(decay, hv, Bv * xs);

        // Coalesced h write: 64 lanes x 4B contiguous
        hp[(size_t)i * (NCH_ * S_)] = hv;

        // Wave-wide sum of hv*Cv via DPP (pure VALU)
        float p = hv * Cv;
        p = DPP_ADD(p, 0x111, 0xf);  // row_shr:1
        p = DPP_ADD(p, 0x112, 0xf);  // row_shr:2
        p = DPP_ADD(p, 0x114, 0xf);  // row_shr:4
        p = DPP_ADD(p, 0x118, 0xf);  // row_shr:8
        p = DPP_ADD(p, 0x142, 0xa);  // row_bcast:15 -> rows 1,3
        p = DPP_ADD(p, 0x143, 0xc);  // row_bcast:31 -> lane63 = total

        // Deposit out value into lane i of outacc
        const float ov = p * readlane_f(sgv, i);
        const float bc = readlane_f(ov, 63);
        outacc = (lane == i) ? bc : outacc;
    }

    // One scatter store: out[seg*64 + lane][bd]
    out[(size_t)(seg * SEG_ + lane) * STRD_ + bd] = outacc;
}

// ---------------- Fallback (R4 single kernel) if ws too small -------------
__global__ __launch_bounds__(256, 2) void slot_elman_fallback(
    const float* __restrict__ x, const float* __restrict__ z,
    const float* __restrict__ h0, const float* __restrict__ dl,
    const float* __restrict__ Bm, const float* __restrict__ C,
    float* __restrict__ out, float* __restrict__ h)
{
    const int nb  = gridDim.x;
    const int cpx = nb >> 3;
    const int bid = blockIdx.x;
    const int swz = (bid & 7) * cpx + (bid >> 3);

    const int wave = swz * (blockDim.x >> 6) + (threadIdx.x >> 6);
    const int lane = threadIdx.x & 63;
    const int bd = wave & (NCH_ - 1);
    const int d  = bd & (D_ - 1);
    const int ds = d * S_ + lane;

    const float decay = sigmoidf_(dl[ds]);
    const float Bv    = Bm[ds];
    const float Cv    = C[lane];

    float hv = h0[(size_t)bd * S_ + lane];
    h[(size_t)bd * S_ + lane] = hv;

    const float* xg_p = x + (size_t)lane * STRD_ + bd;
    const float* zg_p = z + (size_t)lane * STRD_ + bd;
    float*       hp = h + (size_t)(NCH_ * S_) + (size_t)bd * S_ + lane;
    float*       op = out + (size_t)lane * STRD_ + bd;

    float xgA = xg_p[0];
    float zgA = zg_p[0];

    for (int blk = 0; blk < NSEG_; ++blk) {
        const int tb = blk * SEG_;
        const int tbn = (blk + 1 < NSEG_) ? (tb + SEG_) : tb;
        const float xgB = xg_p[(size_t)tbn * STRD_];
        const float zgB = zg_p[(size_t)tbn * STRD_];

        const float sgv = zgA * sigmoidf_(zgA);
        float outacc = 0.0f;

        #pragma unroll 8
        for (int i = 0; i < SEG_; ++i) {
            const float xs = readlane_f(xgA, i);
            hv = fmaf(decay, hv, Bv * xs);
            hp[(size_t)(tb + i) * (NCH_ * S_)] = hv;

            float p = hv * Cv;
            p = DPP_ADD(p, 0x111, 0xf);
            p = DPP_ADD(p, 0x112, 0xf);
            p = DPP_ADD(p, 0x114, 0xf);
            p = DPP_ADD(p, 0x118, 0xf);
            p = DPP_ADD(p, 0x142, 0xa);
            p = DPP_ADD(p, 0x143, 0xc);

            const float ov = p * readlane_f(sgv, i);
            const float bc = readlane_f(ov, 63);
            outacc = (lane == i) ? bc : outacc;
        }
        op[(size_t)tb * STRD_] = outacc;
        xgA = xgB; zgA = zgB;
    }
}

extern "C" void kernel_launch(void* const* d_in, const int* in_sizes, int n_in,
                              void* d_out, int out_size, void* d_ws, size_t ws_size,
                              hipStream_t stream) {
    const float* x  = (const float*)d_in[0];   // [T,Bb,D]
    const float* z  = (const float*)d_in[1];   // [T,Bb,D]
    const float* h0 = (const float*)d_in[2];   // [Bb,D,S]
    const float* dl = (const float*)d_in[3];   // [D,S]
    const float* Bm = (const float*)d_in[4];   // [D,S]
    const float* C  = (const float*)d_in[5];   // [S]

    float* out = (float*)d_out;                            // [T,Bb,D]
    float* h   = (float*)d_out + (size_t)T_ * BB_ * D_;    // [T+1,Bb,D,S]

    if (ws_size >= WS_NEED_) {
        float* ws = (float*)d_ws;
        const int waves = NCH_ * NSEG_;          // 32768
        const int grid  = waves * 64 / 256;      // 8192 blocks of 4 waves
        hipLaunchKernelGGL(slot_elman_pass1, dim3(grid), dim3(256), 0, stream,
                           x, dl, Bm, ws);
        hipLaunchKernelGGL(slot_elman_pass2, dim3(grid), dim3(256), 0, stream,
                           x, z, h0, dl, Bm, C, ws, out, h);
    } else {
        const int waves = NCH_;                  // 2048
        const int grid  = waves * 64 / 256;      // 512
        hipLaunchKernelGGL(slot_elman_fallback, dim3(grid), dim3(256), 0, stream,
                           x, z, h0, dl, Bm, C, out, h);
    }
}

// Round 6
// 152.236 us; speedup vs baseline: 1.0492x; 1.0492x over previous
//
#include <hip/hip_runtime.h>

// SlotElmanCell: T=1024, Bb=2, D=1024, S=64
//   decay = sigmoid(decay_logits)            [D,S]
//   h[t+1] = decay*h[t] + B*x[t]             [Bb,D,S]
//   out[t] = (h[t+1] . C) * silu(z[t])       [Bb,D]
// Outputs (concat flat): out [T,Bb,D] then h [T+1,Bb,D,S]  (f32)
//
// R6: coalesced h-writes. R5 post-mortem: 16x TLP gave zero gain -> limiter
// is the scattered 256B h-store pattern (3.7 TB/s effective vs memset's
// 6.7 TB/s contiguous). Pass2 now uses 1024-thread blocks = 16 consecutive
// chains; h rows are staged in LDS per 16-step group and flushed as
// contiguous 4KB t-slices (16 chains x 256B). out staged likewise.

#define T_    1024
#define BB_   2
#define D_    1024
#define S_    64
#define SEG_  64              // steps per segment
#define NSEG_ (T_ / SEG_)     // 16
#define NCH_  (BB_ * D_)      // 2048 chains
#define STRD_ (BB_ * D_)      // x/z stride between timesteps
#define CHB_  16              // chains per pass2 block
#define FG_   16              // steps per flush group
#define WS_NEED_ ((size_t)NCH_ * NSEG_ * S_ * 4)   // 8 MB

// x + dpp_shifted(x); bound_ctrl=1 -> out-of-range sources read 0.
#define DPP_ADD(x, ctrl, rm) \
  ((x) + __int_as_float(__builtin_amdgcn_update_dpp( \
        0, __float_as_int(x), (ctrl), (rm), 0xf, true)))

__device__ __forceinline__ float readlane_f(float v, int lane) {
    return __int_as_float(__builtin_amdgcn_readlane(__float_as_int(v), lane));
}

__device__ __forceinline__ float sigmoidf_(float v) {
    return 1.0f / (1.0f + __expf(-v));
}

// ---------------- Pass 1: per-segment local scans (zero init) -------------
__global__ __launch_bounds__(256, 8) void slot_elman_pass1(
    const float* __restrict__ x, const float* __restrict__ dl,
    const float* __restrict__ Bm, float* __restrict__ ws)
{
    const int wave = blockIdx.x * (blockDim.x >> 6) + (threadIdx.x >> 6);
    const int lane = threadIdx.x & 63;
    const int bd   = wave & (NCH_ - 1);     // chain
    const int seg  = wave >> 11;            // segment
    const int d    = bd & (D_ - 1);
    const int ds   = d * S_ + lane;

    const float decay = sigmoidf_(dl[ds]);
    const float Bv    = Bm[ds];

    const float xg = x[(size_t)(seg * SEG_ + lane) * STRD_ + bd];

    float hl = 0.0f;
    #pragma unroll
    for (int i = 0; i < SEG_; ++i)
        hl = fmaf(decay, hl, Bv * readlane_f(xg, i));

    ws[(size_t)(bd * NSEG_ + seg) * S_ + lane] = hl;
}

// ---------------- Pass 2: fold start state, scan, staged writes -----------
__global__ __launch_bounds__(1024, 8) void slot_elman_pass2(
    const float* __restrict__ x, const float* __restrict__ z,
    const float* __restrict__ h0, const float* __restrict__ dl,
    const float* __restrict__ Bm, const float* __restrict__ C,
    const float* __restrict__ ws,
    float* __restrict__ out, float* __restrict__ h)
{
    __shared__ float stage[FG_ * CHB_ * S_];   // 64 KB

    // Bijective XCD swizzle (2048 blocks, 256/XCD). Same-XCD blocks get
    // consecutive chain-groups of the SAME segment -> adjacent 4KB writes.
    const int bid = blockIdx.x;
    const int cpx = gridDim.x >> 3;                 // 256
    const int swz = (bid & 7) * cpx + (bid >> 3);
    const int seg = swz >> 7;                       // 0..15
    const int g   = swz & 127;                      // chain group

    const int w    = threadIdx.x >> 6;              // wave 0..15
    const int lane = threadIdx.x & 63;              // slot s
    const int bd   = g * CHB_ + w;
    const int d    = bd & (D_ - 1);
    const int ds   = d * S_ + lane;

    const float decay = sigmoidf_(dl[ds]);
    const float Bv    = Bm[ds];
    const float Cv    = C[lane];

    // decay^64 by repeated squaring
    float dk = decay * decay;
    dk = dk * dk; dk = dk * dk; dk = dk * dk; dk = dk * dk;
    const float d64 = dk * dk;

    // Segment start state: h0 folded with previous segments' local sums.
    float hv = h0[(size_t)bd * S_ + lane];
    if (seg == 0)
        h[(size_t)bd * S_ + lane] = hv;             // h[0] slice

    const float* wp = ws + (size_t)bd * NSEG_ * S_ + lane;
    #pragma unroll
    for (int j = 0; j < NSEG_ - 1; ++j) {
        const float lj = wp[(size_t)j * S_];
        const float wgt = (j < seg) ? d64 : 1.0f;
        const float add = (j < seg) ? lj  : 0.0f;
        hv = fmaf(wgt, hv, add);
    }

    // Gathers: lane l covers t = seg*64 + l (block's waves share lines)
    const float xgA = x[(size_t)(seg * SEG_ + lane) * STRD_ + bd];
    const float zgA = z[(size_t)(seg * SEG_ + lane) * STRD_ + bd];
    const float sgv = zgA * sigmoidf_(zgA);         // silu, lane = t

    float outacc = 0.0f;

    for (int f = 0; f < SEG_ / FG_; ++f) {          // 4 groups of 16 steps
        #pragma unroll
        for (int li = 0; li < FG_; ++li) {
            const int i = f * FG_ + li;             // segment-local step
            const float xs = readlane_f(xgA, i);

            hv = fmaf(decay, hv, Bv * xs);          // recurrence

            // Stage h row: [li][chain w][slot] -> bank = lane%32 (2-way, free)
            stage[(li * CHB_ + w) * S_ + lane] = hv;

            // Wave-wide sum of hv*Cv via DPP (pure VALU)
            float p = hv * Cv;
            p = DPP_ADD(p, 0x111, 0xf);  // row_shr:1
            p = DPP_ADD(p, 0x112, 0xf);  // row_shr:2
            p = DPP_ADD(p, 0x114, 0xf);  // row_shr:4
            p = DPP_ADD(p, 0x118, 0xf);  // row_shr:8
            p = DPP_ADD(p, 0x142, 0xa);  // row_bcast:15
            p = DPP_ADD(p, 0x143, 0xc);  // row_bcast:31 -> lane63 = total

            const float ov = p * readlane_f(sgv, i);
            const float bc = readlane_f(ov, 63);
            outacc = (lane == i) ? bc : outacc;     // deposit lane i
        }

        __syncthreads();

        // Flush: wave w takes t-slice li=w -> ONE contiguous 4KB chunk
        {
            const int t1 = seg * SEG_ + f * FG_ + w + 1;  // h slice index
            const float4* src = (const float4*)&stage[w * CHB_ * S_];
            float4* dst = (float4*)&h[((size_t)t1 * NCH_ + (size_t)g * CHB_) * S_];
            dst[lane]       = src[lane];
            dst[lane + 64]  = src[lane + 64];
            dst[lane + 128] = src[lane + 128];
            dst[lane + 192] = src[lane + 192];
        }

        __syncthreads();
    }

    // out staging: [t-local][chain] with pad-17 stride (conflict-free)
    stage[lane * 17 + w] = outacc;
    __syncthreads();
    {
        const int tl = threadIdx.x >> 4;            // 0..63
        const int c  = threadIdx.x & 15;            // chain in group
        out[(size_t)(seg * SEG_ + tl) * STRD_ + (size_t)g * CHB_ + c] =
            stage[tl * 17 + c];
    }
}

// ---------------- Fallback (R4 single kernel) if ws too small -------------
__global__ __launch_bounds__(256, 2) void slot_elman_fallback(
    const float* __restrict__ x, const float* __restrict__ z,
    const float* __restrict__ h0, const float* __restrict__ dl,
    const float* __restrict__ Bm, const float* __restrict__ C,
    float* __restrict__ out, float* __restrict__ h)
{
    const int nb  = gridDim.x;
    const int cpx = nb >> 3;
    const int bid = blockIdx.x;
    const int swz = (bid & 7) * cpx + (bid >> 3);

    const int wave = swz * (blockDim.x >> 6) + (threadIdx.x >> 6);
    const int lane = threadIdx.x & 63;
    const int bd = wave & (NCH_ - 1);
    const int d  = bd & (D_ - 1);
    const int ds = d * S_ + lane;

    const float decay = sigmoidf_(dl[ds]);
    const float Bv    = Bm[ds];
    const float Cv    = C[lane];

    float hv = h0[(size_t)bd * S_ + lane];
    h[(size_t)bd * S_ + lane] = hv;

    const float* xg_p = x + (size_t)lane * STRD_ + bd;
    const float* zg_p = z + (size_t)lane * STRD_ + bd;
    float*       hp = h + (size_t)(NCH_ * S_) + (size_t)bd * S_ + lane;
    float*       op = out + (size_t)lane * STRD_ + bd;

    float xgA = xg_p[0];
    float zgA = zg_p[0];

    for (int blk = 0; blk < NSEG_; ++blk) {
        const int tb = blk * SEG_;
        const int tbn = (blk + 1 < NSEG_) ? (tb + SEG_) : tb;
        const float xgB = xg_p[(size_t)tbn * STRD_];
        const float zgB = zg_p[(size_t)tbn * STRD_];

        const float sgv = zgA * sigmoidf_(zgA);
        float outacc = 0.0f;

        #pragma unroll 8
        for (int i = 0; i < SEG_; ++i) {
            const float xs = readlane_f(xgA, i);
            hv = fmaf(decay, hv, Bv * xs);
            hp[(size_t)(tb + i) * (NCH_ * S_)] = hv;

            float p = hv * Cv;
            p = DPP_ADD(p, 0x111, 0xf);
            p = DPP_ADD(p, 0x112, 0xf);
            p = DPP_ADD(p, 0x114, 0xf);
            p = DPP_ADD(p, 0x118, 0xf);
            p = DPP_ADD(p, 0x142, 0xa);
            p = DPP_ADD(p, 0x143, 0xc);

            const float ov = p * readlane_f(sgv, i);
            const float bc = readlane_f(ov, 63);
            outacc = (lane == i) ? bc : outacc;
        }
        op[(size_t)tb * STRD_] = outacc;
        xgA = xgB; zgA = zgB;
    }
}

extern "C" void kernel_launch(void* const* d_in, const int* in_sizes, int n_in,
                              void* d_out, int out_size, void* d_ws, size_t ws_size,
                              hipStream_t stream) {
    const float* x  = (const float*)d_in[0];   // [T,Bb,D]
    const float* z  = (const float*)d_in[1];   // [T,Bb,D]
    const float* h0 = (const float*)d_in[2];   // [Bb,D,S]
    const float* dl = (const float*)d_in[3];   // [D,S]
    const float* Bm = (const float*)d_in[4];   // [D,S]
    const float* C  = (const float*)d_in[5];   // [S]

    float* out = (float*)d_out;                            // [T,Bb,D]
    float* h   = (float*)d_out + (size_t)T_ * BB_ * D_;    // [T+1,Bb,D,S]

    if (ws_size >= WS_NEED_) {
        float* ws = (float*)d_ws;
        const int waves1 = NCH_ * NSEG_;          // 32768
        const int grid1  = waves1 * 64 / 256;     // 8192
        hipLaunchKernelGGL(slot_elman_pass1, dim3(grid1), dim3(256), 0, stream,
                           x, dl, Bm, ws);
        const int grid2  = (NCH_ / CHB_) * NSEG_; // 128 * 16 = 2048
        hipLaunchKernelGGL(slot_elman_pass2, dim3(grid2), dim3(1024), 0, stream,
                           x, z, h0, dl, Bm, C, ws, out, h);
    } else {
        const int waves = NCH_;                   // 2048
        const int grid  = waves * 64 / 256;       // 512
        hipLaunchKernelGGL(slot_elman_fallback, dim3(grid), dim3(256), 0, stream,
                           x, z, h0, dl, Bm, C, out, h);
    }
}

// Round 7
// 125.688 us; speedup vs baseline: 1.2708x; 1.2112x over previous
//
#include <hip/hip_runtime.h>

// SlotElmanCell: T=1024, Bb=2, D=1024, S=64
//   decay = sigmoid(decay_logits)            [D,S]
//   h[t+1] = decay*h[t] + B*x[t]             [Bb,D,S]
//   out[t] = (h[t+1] . C) * silu(z[t])       [Bb,D]
// Outputs (concat flat): out [T,Bb,D] then h [T+1,Bb,D,S]  (f32)
//
// R7 = R6 with ONE change: pass2 block ordering. R6 (null) spread the
// resident-block window over 8 segments -> device-instant writes = 8
// scattered 4KB-granule windows -> DRAM row misses (~3.7 TB/s). Now
// seg = bid>>7, g = bid&127: the ~512 resident blocks cover segs 0..3
// with ALL 128 chain-groups each, so every t-slice is written as a full
// contiguous 512KB device-wide sweep (fillBuffer-like stream).

#define T_    1024
#define BB_   2
#define D_    1024
#define S_    64
#define SEG_  64              // steps per segment
#define NSEG_ (T_ / SEG_)     // 16
#define NCH_  (BB_ * D_)      // 2048 chains
#define STRD_ (BB_ * D_)      // x/z stride between timesteps
#define CHB_  16              // chains per pass2 block
#define FG_   16              // steps per flush group
#define WS_NEED_ ((size_t)NCH_ * NSEG_ * S_ * 4)   // 8 MB

// x + dpp_shifted(x); bound_ctrl=1 -> out-of-range sources read 0.
#define DPP_ADD(x, ctrl, rm) \
  ((x) + __int_as_float(__builtin_amdgcn_update_dpp( \
        0, __float_as_int(x), (ctrl), (rm), 0xf, true)))

__device__ __forceinline__ float readlane_f(float v, int lane) {
    return __int_as_float(__builtin_amdgcn_readlane(__float_as_int(v), lane));
}

__device__ __forceinline__ float sigmoidf_(float v) {
    return 1.0f / (1.0f + __expf(-v));
}

// ---------------- Pass 1: per-segment local scans (zero init) -------------
__global__ __launch_bounds__(256, 8) void slot_elman_pass1(
    const float* __restrict__ x, const float* __restrict__ dl,
    const float* __restrict__ Bm, float* __restrict__ ws)
{
    const int wave = blockIdx.x * (blockDim.x >> 6) + (threadIdx.x >> 6);
    const int lane = threadIdx.x & 63;
    const int bd   = wave & (NCH_ - 1);     // chain
    const int seg  = wave >> 11;            // segment
    const int d    = bd & (D_ - 1);
    const int ds   = d * S_ + lane;

    const float decay = sigmoidf_(dl[ds]);
    const float Bv    = Bm[ds];

    const float xg = x[(size_t)(seg * SEG_ + lane) * STRD_ + bd];

    float hl = 0.0f;
    #pragma unroll
    for (int i = 0; i < SEG_; ++i)
        hl = fmaf(decay, hl, Bv * readlane_f(xg, i));

    ws[(size_t)(bd * NSEG_ + seg) * S_ + lane] = hl;
}

// ---------------- Pass 2: fold start state, scan, staged writes -----------
__global__ __launch_bounds__(1024, 8) void slot_elman_pass2(
    const float* __restrict__ x, const float* __restrict__ z,
    const float* __restrict__ h0, const float* __restrict__ dl,
    const float* __restrict__ Bm, const float* __restrict__ C,
    const float* __restrict__ ws,
    float* __restrict__ out, float* __restrict__ h)
{
    __shared__ float stage[FG_ * CHB_ * S_];   // 64 KB

    // Seg-major ordering: resident window (~512 blocks) = segs 0..3 with
    // all 128 chain-groups -> each t-slice written as contiguous 512KB
    // device-wide. (R6's XCD swizzle spread the window over 8 segs.)
    const int bid = blockIdx.x;
    const int seg = bid >> 7;                       // 0..15
    const int g   = bid & 127;                      // chain group

    const int w    = threadIdx.x >> 6;              // wave 0..15
    const int lane = threadIdx.x & 63;              // slot s
    const int bd   = g * CHB_ + w;
    const int d    = bd & (D_ - 1);
    const int ds   = d * S_ + lane;

    const float decay = sigmoidf_(dl[ds]);
    const float Bv    = Bm[ds];
    const float Cv    = C[lane];

    // decay^64 by repeated squaring
    float dk = decay * decay;
    dk = dk * dk; dk = dk * dk; dk = dk * dk; dk = dk * dk;
    const float d64 = dk * dk;

    // Segment start state: h0 folded with previous segments' local sums.
    float hv = h0[(size_t)bd * S_ + lane];
    if (seg == 0)
        h[(size_t)bd * S_ + lane] = hv;             // h[0] slice

    const float* wp = ws + (size_t)bd * NSEG_ * S_ + lane;
    #pragma unroll
    for (int j = 0; j < NSEG_ - 1; ++j) {
        const float lj = wp[(size_t)j * S_];
        const float wgt = (j < seg) ? d64 : 1.0f;
        const float add = (j < seg) ? lj  : 0.0f;
        hv = fmaf(wgt, hv, add);
    }

    // Gathers: lane l covers t = seg*64 + l
    const float xgA = x[(size_t)(seg * SEG_ + lane) * STRD_ + bd];
    const float zgA = z[(size_t)(seg * SEG_ + lane) * STRD_ + bd];
    const float sgv = zgA * sigmoidf_(zgA);         // silu, lane = t

    float outacc = 0.0f;

    for (int f = 0; f < SEG_ / FG_; ++f) {          // 4 groups of 16 steps
        #pragma unroll
        for (int li = 0; li < FG_; ++li) {
            const int i = f * FG_ + li;             // segment-local step
            const float xs = readlane_f(xgA, i);

            hv = fmaf(decay, hv, Bv * xs);          // recurrence

            // Stage h row: [li][chain w][slot] -> 2-way bank alias (free)
            stage[(li * CHB_ + w) * S_ + lane] = hv;

            // Wave-wide sum of hv*Cv via DPP (pure VALU)
            float p = hv * Cv;
            p = DPP_ADD(p, 0x111, 0xf);  // row_shr:1
            p = DPP_ADD(p, 0x112, 0xf);  // row_shr:2
            p = DPP_ADD(p, 0x114, 0xf);  // row_shr:4
            p = DPP_ADD(p, 0x118, 0xf);  // row_shr:8
            p = DPP_ADD(p, 0x142, 0xa);  // row_bcast:15
            p = DPP_ADD(p, 0x143, 0xc);  // row_bcast:31 -> lane63 = total

            const float ov = p * readlane_f(sgv, i);
            const float bc = readlane_f(ov, 63);
            outacc = (lane == i) ? bc : outacc;     // deposit lane i
        }

        __syncthreads();

        // Flush: wave w takes t-slice li=w -> ONE contiguous 4KB chunk;
        // 128 same-seg blocks together cover the full 512KB t-slice.
        {
            const int t1 = seg * SEG_ + f * FG_ + w + 1;  // h slice index
            const float4* src = (const float4*)&stage[w * CHB_ * S_];
            float4* dst = (float4*)&h[((size_t)t1 * NCH_ + (size_t)g * CHB_) * S_];
            dst[lane]       = src[lane];
            dst[lane + 64]  = src[lane + 64];
            dst[lane + 128] = src[lane + 128];
            dst[lane + 192] = src[lane + 192];
        }

        __syncthreads();
    }

    // out staging: [t-local][chain] with pad-17 stride (conflict-free)
    stage[lane * 17 + w] = outacc;
    __syncthreads();
    {
        const int tl = threadIdx.x >> 4;            // 0..63
        const int c  = threadIdx.x & 15;            // chain in group
        out[(size_t)(seg * SEG_ + tl) * STRD_ + (size_t)g * CHB_ + c] =
            stage[tl * 17 + c];
    }
}

// ---------------- Fallback (R4 single kernel) if ws too small -------------
__global__ __launch_bounds__(256, 2) void slot_elman_fallback(
    const float* __restrict__ x, const float* __restrict__ z,
    const float* __restrict__ h0, const float* __restrict__ dl,
    const float* __restrict__ Bm, const float* __restrict__ C,
    float* __restrict__ out, float* __restrict__ h)
{
    const int nb  = gridDim.x;
    const int cpx = nb >> 3;
    const int bid = blockIdx.x;
    const int swz = (bid & 7) * cpx + (bid >> 3);

    const int wave = swz * (blockDim.x >> 6) + (threadIdx.x >> 6);
    const int lane = threadIdx.x & 63;
    const int bd = wave & (NCH_ - 1);
    const int d  = bd & (D_ - 1);
    const int ds = d * S_ + lane;

    const float decay = sigmoidf_(dl[ds]);
    const float Bv    = Bm[ds];
    const float Cv    = C[lane];

    float hv = h0[(size_t)bd * S_ + lane];
    h[(size_t)bd * S_ + lane] = hv;

    const float* xg_p = x + (size_t)lane * STRD_ + bd;
    const float* zg_p = z + (size_t)lane * STRD_ + bd;
    float*       hp = h + (size_t)(NCH_ * S_) + (size_t)bd * S_ + lane;
    float*       op = out + (size_t)lane * STRD_ + bd;

    float xgA = xg_p[0];
    float zgA = zg_p[0];

    for (int blk = 0; blk < NSEG_; ++blk) {
        const int tb = blk * SEG_;
        const int tbn = (blk + 1 < NSEG_) ? (tb + SEG_) : tb;
        const float xgB = xg_p[(size_t)tbn * STRD_];
        const float zgB = zg_p[(size_t)tbn * STRD_];

        const float sgv = zgA * sigmoidf_(zgA);
        float outacc = 0.0f;

        #pragma unroll 8
        for (int i = 0; i < SEG_; ++i) {
            const float xs = readlane_f(xgA, i);
            hv = fmaf(decay, hv, Bv * xs);
            hp[(size_t)(tb + i) * (NCH_ * S_)] = hv;

            float p = hv * Cv;
            p = DPP_ADD(p, 0x111, 0xf);
            p = DPP_ADD(p, 0x112, 0xf);
            p = DPP_ADD(p, 0x114, 0xf);
            p = DPP_ADD(p, 0x118, 0xf);
            p = DPP_ADD(p, 0x142, 0xa);
            p = DPP_ADD(p, 0x143, 0xc);

            const float ov = p * readlane_f(sgv, i);
            const float bc = readlane_f(ov, 63);
            outacc = (lane == i) ? bc : outacc;
        }
        op[(size_t)tb * STRD_] = outacc;
        xgA = xgB; zgA = zgB;
    }
}

extern "C" void kernel_launch(void* const* d_in, const int* in_sizes, int n_in,
                              void* d_out, int out_size, void* d_ws, size_t ws_size,
                              hipStream_t stream) {
    const float* x  = (const float*)d_in[0];   // [T,Bb,D]
    const float* z  = (const float*)d_in[1];   // [T,Bb,D]
    const float* h0 = (const float*)d_in[2];   // [Bb,D,S]
    const float* dl = (const float*)d_in[3];   // [D,S]
    const float* Bm = (const float*)d_in[4];   // [D,S]
    const float* C  = (const float*)d_in[5];   // [S]

    float* out = (float*)d_out;                            // [T,Bb,D]
    float* h   = (float*)d_out + (size_t)T_ * BB_ * D_;    // [T+1,Bb,D,S]

    if (ws_size >= WS_NEED_) {
        float* ws = (float*)d_ws;
        const int waves1 = NCH_ * NSEG_;          // 32768
        const int grid1  = waves1 * 64 / 256;     // 8192
        hipLaunchKernelGGL(slot_elman_pass1, dim3(grid1), dim3(256), 0, stream,
                           x, dl, Bm, ws);
        const int grid2  = (NCH_ / CHB_) * NSEG_; // 128 * 16 = 2048
        hipLaunchKernelGGL(slot_elman_pass2, dim3(grid2), dim3(1024), 0, stream,
                           x, z, h0, dl, Bm, C, ws, out, h);
    } else {
        const int waves = NCH_;                   // 2048
        const int grid  = waves * 64 / 256;       // 512
        hipLaunchKernelGGL(slot_elman_fallback, dim3(grid), dim3(256), 0, stream,
                           x, z, h0, dl, Bm, C, out, h);
    }
}